// Round 1
// baseline (291.213 us; speedup 1.0000x reference)
//
#include <hip/hip_runtime.h>
#include <hip/hip_bf16.h>

// LeWinAttention: q/kv projection + scrambled-reshape windowed attention + out projection.
// Key fact: after the reference's raw reshapes, every attention batch b' uses
// CONTIGUOUS 256x64 (Q) / 512x64 (K,V) row-major bf16 tiles at offsets
// b'*16384 / 2*b'*16384, and writes its output back at b'*16384 in q's layout.

typedef unsigned short u16;
using bfrag = __attribute__((ext_vector_type(8))) short;   // 8 x bf16
using ffrag = __attribute__((ext_vector_type(4))) float;   // 4 x f32 accum

#define MFMA16(a, b, c) __builtin_amdgcn_mfma_f32_16x16x32_bf16((a), (b), (c), 0, 0, 0)

__device__ __forceinline__ u16 f2bf(float f) {
    __hip_bfloat16 h = __float2bfloat16(f);
    u16 u;
    __builtin_memcpy(&u, &h, 2);
    return u;
}

// ---------------------------------------------------------------------------
// Kernel 1: fused Q/K/V projection (bf16 MFMA, K=128) + RoPE epilogue.
// grid = (128 pos-tiles, 40 row-tiles), block = 256.
// row-tiles: 0..7 -> q (b = tr>>2, o0 = (tr&3)*128); 8..39 -> kv.
// ---------------------------------------------------------------------------
__global__ __launch_bounds__(256) void k_proj(
    const float* __restrict__ x, const float* __restrict__ skip,
    const float* __restrict__ sinp, const float* __restrict__ cosp,
    const float* __restrict__ Wq, const float* __restrict__ Wkv,
    u16* __restrict__ qb, u16* __restrict__ kbuf, u16* __restrict__ vbuf)
{
    __shared__ u16 xT[128 * 136];   // [pos_local][c], pitch 136 (272B = 17*16B)
    const int t = threadIdx.x;
    const int pos0 = blockIdx.x * 128;
    const int tr = blockIdx.y;

    const float* W;
    const float* src;
    u16* dst;
    int mode;  // 0 = none (v), 1 = q-rope, 2 = k-rope
    if (tr < 8) {
        int b = tr >> 2, o0 = (tr & 3) * 128;
        W = Wq + o0 * 128;
        src = x + (size_t)b * 2097152;
        dst = qb + (size_t)b * 8388608 + (size_t)o0 * 16384;
        mode = 1;
    } else {
        int t2 = tr - 8;
        int bkv = t2 >> 3, oo0 = (t2 & 7) * 128;
        W = Wkv + oo0 * 128;
        src = (bkv < 2) ? (x + (size_t)bkv * 2097152)
                        : (skip + (size_t)(bkv - 2) * 2097152);
        if (oo0 < 512) {
            dst = kbuf + (size_t)bkv * 8388608 + (size_t)oo0 * 16384;
            mode = 2;
        } else {
            dst = vbuf + (size_t)bkv * 8388608 + (size_t)(oo0 - 512) * 16384;
            mode = 0;
        }
    }

    // stage x tile transposed: global [c][pos] f32 -> LDS [pos][c] bf16
#pragma unroll
    for (int it = 0; it < 16; ++it) {
        int f = it * 256 + t;      // float4 index, 4096 total
        int c = f >> 5;            // 32 float4 per c-row
        int po = (f & 31) * 4;
        float4 v = *(const float4*)(src + (size_t)c * 16384 + pos0 + po);
        xT[(po + 0) * 136 + c] = f2bf(v.x);
        xT[(po + 1) * 136 + c] = f2bf(v.y);
        xT[(po + 2) * 136 + c] = f2bf(v.z);
        xT[(po + 3) * 136 + c] = f2bf(v.w);
    }

    const int w = t >> 6, l = t & 63, lr = l & 15, lg = l >> 4;
    const int wm = w >> 1, wn = w & 1;  // wave -> 64 rows x 64 cols quadrant

    // A-frags: W rows from global f32 (cached; tiny matrix), cast bf16
    bfrag A[4][4];
#pragma unroll
    for (int rb = 0; rb < 4; ++rb)
#pragma unroll
        for (int kk = 0; kk < 4; ++kk) {
            const float* p = W + (wm * 64 + rb * 16 + lr) * 128 + kk * 32 + lg * 8;
            float4 a0 = *(const float4*)p;
            float4 a1 = *(const float4*)(p + 4);
            bfrag a;
            a[0] = (short)f2bf(a0.x); a[1] = (short)f2bf(a0.y);
            a[2] = (short)f2bf(a0.z); a[3] = (short)f2bf(a0.w);
            a[4] = (short)f2bf(a1.x); a[5] = (short)f2bf(a1.y);
            a[6] = (short)f2bf(a1.z); a[7] = (short)f2bf(a1.w);
            A[rb][kk] = a;
        }

    ffrag zf = {0.f, 0.f, 0.f, 0.f};
    ffrag acc[4][4];
#pragma unroll
    for (int rb = 0; rb < 4; ++rb)
#pragma unroll
        for (int nb = 0; nb < 4; ++nb) acc[rb][nb] = zf;

    __syncthreads();

#pragma unroll
    for (int kk = 0; kk < 4; ++kk) {
        bfrag B[4];
#pragma unroll
        for (int nb = 0; nb < 4; ++nb)
            B[nb] = *(const bfrag*)&xT[(wn * 64 + nb * 16 + lr) * 136 + kk * 32 + lg * 8];
#pragma unroll
        for (int rb = 0; rb < 4; ++rb)
#pragma unroll
            for (int nb = 0; nb < 4; ++nb)
                acc[rb][nb] = MFMA16(A[rb][kk], B[nb], acc[rb][nb]);
    }

    // epilogue: RoPE (exact reference semantics, incl. the k "+cos" form) + bf16 store
#pragma unroll
    for (int rb = 0; rb < 4; ++rb)
#pragma unroll
        for (int nb = 0; nb < 4; ++nb) {
            int posb = pos0 + wn * 64 + nb * 16 + lr;
            int hh = posb >> 7, ww = posb & 127, s = ww & 63;
            bool roped = (mode != 0) && (s < 32);
#pragma unroll
            for (int r = 0; r < 4; ++r) {
                int row = wm * 64 + rb * 16 + lg * 4 + r;
                float v = acc[rb][nb][r];
                if (roped) {
                    int pidx = (row & 63) * 2 + (hh >> 6);
                    int ridx = (hh & 63) * 2 + (ww >> 6);
                    int sidx = (pidx * 128 + ridx) * 32 + s;
                    float sv = sinp[sidx], cv = cosp[sidx];
                    float sg = (s & 1) ? sv : -sv;        // rotate_half: -even, +odd
                    v = (mode == 1) ? v * (cv + sg)       // q: q*cos + rot(q)*sin
                                    : v * (1.f + sg) + cv; // k: k + cos + rot(k)*sin
                }
                dst[(size_t)row * 16384 + posb] = f2bf(v);
            }
        }
}

// ---------------------------------------------------------------------------
// Kernel 2: windowed attention, 1024 batches, one block (4 waves) per batch.
// Q (256x64) in registers per wave; K,V chunks (64x64) staged in LDS; softmax
// without max-subtraction (|sim| <= ~4 analytically); P via per-wave LDS.
// Output written IN-PLACE over the q buffer (disjoint per block).
// ---------------------------------------------------------------------------
__global__ __launch_bounds__(256) void k_attn(
    const u16* __restrict__ qb, const u16* __restrict__ kbuf,
    const u16* __restrict__ vbuf, u16* __restrict__ ob)
{
    __shared__ u16 Ks[64 * 72];      // [j][s] pitch 72
    __shared__ u16 Vt[64 * 72];      // [s][j] pitch 72 (transposed)
    __shared__ u16 Ps[4][64 * 72];   // per-wave P [i][j]
    const int bp = blockIdx.x;
    const int t = threadIdx.x, w = t >> 6, l = t & 63, lr = l & 15, lg = l >> 4;

    const u16* Qg = qb + (size_t)bp * 16384 + w * 4096;  // wave's 64 q-rows
    const u16* Kg = kbuf + (size_t)bp * 32768;
    const u16* Vg = vbuf + (size_t)bp * 32768;

    bfrag Qf[4][2];
#pragma unroll
    for (int rb = 0; rb < 4; ++rb)
#pragma unroll
        for (int kk = 0; kk < 2; ++kk)
            Qf[rb][kk] = *(const bfrag*)(Qg + (rb * 16 + lr) * 64 + kk * 32 + lg * 8);

    ffrag zf = {0.f, 0.f, 0.f, 0.f};
    ffrag Oacc[4][4];
    float Ls[4][4];
#pragma unroll
    for (int rb = 0; rb < 4; ++rb) {
#pragma unroll
        for (int sb = 0; sb < 4; ++sb) Oacc[rb][sb] = zf;
#pragma unroll
        for (int r = 0; r < 4; ++r) Ls[rb][r] = 0.f;
    }

    const int sj = t >> 2, ss0 = (t & 3) * 16;  // staging: 16 elems/thread

    for (int c = 0; c < 8; ++c) {
        __syncthreads();
        {
            const u16* kc_ = Kg + c * 4096;
            uint4 k0 = *(const uint4*)(kc_ + sj * 64 + ss0);
            uint4 k1 = *(const uint4*)(kc_ + sj * 64 + ss0 + 8);
            *(uint4*)&Ks[sj * 72 + ss0] = k0;
            *(uint4*)&Ks[sj * 72 + ss0 + 8] = k1;
            const u16* vc_ = Vg + c * 4096;
            uint4 v0 = *(const uint4*)(vc_ + sj * 64 + ss0);
            uint4 v1 = *(const uint4*)(vc_ + sj * 64 + ss0 + 8);
            u16 tmp[16];
            *(uint4*)&tmp[0] = v0;
            *(uint4*)&tmp[8] = v1;
#pragma unroll
            for (int e = 0; e < 16; ++e)
                Vt[(ss0 + e) * 72 + sj] = tmp[e];  // transpose V
        }
        __syncthreads();

        // S = Q K^T (B-operand = K rows read as k-contiguous b128)
        bfrag Bf[2][4];
#pragma unroll
        for (int kk = 0; kk < 2; ++kk)
#pragma unroll
            for (int cb = 0; cb < 4; ++cb)
                Bf[kk][cb] = *(const bfrag*)&Ks[(cb * 16 + lr) * 72 + kk * 32 + lg * 8];

#pragma unroll
        for (int rb = 0; rb < 4; ++rb) {
            float rsum[4] = {0.f, 0.f, 0.f, 0.f};
#pragma unroll
            for (int cb = 0; cb < 4; ++cb) {
                ffrag sf = zf;
                sf = MFMA16(Qf[rb][0], Bf[0][cb], sf);
                sf = MFMA16(Qf[rb][1], Bf[1][cb], sf);
#pragma unroll
                for (int r = 0; r < 4; ++r) {
                    float e = __expf(sf[r] * 0.125f);  // SCALE = 1/sqrt(64)
                    rsum[r] += e;
                    Ps[w][(rb * 16 + lg * 4 + r) * 72 + cb * 16 + lr] = f2bf(e);
                }
            }
#pragma unroll
            for (int r = 0; r < 4; ++r) {  // row-sum across the 16 col-lanes
                float v = rsum[r];
                v += __shfl_xor(v, 1);
                v += __shfl_xor(v, 2);
                v += __shfl_xor(v, 4);
                v += __shfl_xor(v, 8);
                Ls[rb][r] += v;
            }
        }

        // O += P * V
#pragma unroll
        for (int kk = 0; kk < 2; ++kk) {
            bfrag Vf[4];
#pragma unroll
            for (int sb = 0; sb < 4; ++sb)
                Vf[sb] = *(const bfrag*)&Vt[(sb * 16 + lr) * 72 + kk * 32 + lg * 8];
#pragma unroll
            for (int rb = 0; rb < 4; ++rb) {
                bfrag Pf = *(const bfrag*)&Ps[w][(rb * 16 + lr) * 72 + kk * 32 + lg * 8];
#pragma unroll
                for (int sb = 0; sb < 4; ++sb)
                    Oacc[rb][sb] = MFMA16(Pf, Vf[sb], Oacc[rb][sb]);
            }
        }
    }

    u16* og = ob + (size_t)bp * 16384 + w * 4096;
#pragma unroll
    for (int rb = 0; rb < 4; ++rb) {
        float inv[4];
#pragma unroll
        for (int r = 0; r < 4; ++r) inv[r] = 1.f / Ls[rb][r];
#pragma unroll
        for (int sb = 0; sb < 4; ++sb)
#pragma unroll
            for (int r = 0; r < 4; ++r)
                og[(rb * 16 + lg * 4 + r) * 64 + sb * 16 + lr] =
                    f2bf(Oacc[rb][sb][r] * inv[r]);
    }
}

// ---------------------------------------------------------------------------
// Kernel 3: output projection out[b][o2][pos] = sum_c2 Wout[o2][c2]*ob[b][c2][pos]
// M=128 (all o2), K=512 in 4 chunks, N=128 pos per block. grid=(128,2).
// ---------------------------------------------------------------------------
__global__ __launch_bounds__(256) void k_out(
    const u16* __restrict__ ob, const float* __restrict__ Wout,
    float* __restrict__ out)
{
    __shared__ u16 obT[128 * 136];  // [pos][c2_local]
    const int t = threadIdx.x, w = t >> 6, l = t & 63, lr = l & 15, lg = l >> 4;
    const int pos0 = blockIdx.x * 128;
    const int b = blockIdx.y;
    const u16* obp = ob + (size_t)b * 8388608;
    float* op = out + (size_t)b * 2097152;

    ffrag zf = {0.f, 0.f, 0.f, 0.f};
    ffrag acc[2][8];
#pragma unroll
    for (int rb = 0; rb < 2; ++rb)
#pragma unroll
        for (int nb = 0; nb < 8; ++nb) acc[rb][nb] = zf;

    for (int kc = 0; kc < 4; ++kc) {
        __syncthreads();
#pragma unroll
        for (int r8 = 0; r8 < 8; ++r8) {
            int cl = (t >> 4) + 16 * r8;
            int po = (t & 15) * 8;
            uint4 v = *(const uint4*)(obp + (size_t)(kc * 128 + cl) * 16384 + pos0 + po);
            u16 tmp[8];
            *(uint4*)tmp = v;
#pragma unroll
            for (int e = 0; e < 8; ++e)
                obT[(po + e) * 136 + cl] = tmp[e];
        }
        __syncthreads();

#pragma unroll
        for (int kk = 0; kk < 4; ++kk) {
            bfrag Af[2];
#pragma unroll
            for (int rb = 0; rb < 2; ++rb) {
                const float* p = Wout + (w * 32 + rb * 16 + lr) * 512 + kc * 128 + kk * 32 + lg * 8;
                float4 a0 = *(const float4*)p;
                float4 a1 = *(const float4*)(p + 4);
                bfrag a;
                a[0] = (short)f2bf(a0.x); a[1] = (short)f2bf(a0.y);
                a[2] = (short)f2bf(a0.z); a[3] = (short)f2bf(a0.w);
                a[4] = (short)f2bf(a1.x); a[5] = (short)f2bf(a1.y);
                a[6] = (short)f2bf(a1.z); a[7] = (short)f2bf(a1.w);
                Af[rb] = a;
            }
#pragma unroll
            for (int nb = 0; nb < 8; ++nb) {
                bfrag B = *(const bfrag*)&obT[(nb * 16 + lr) * 136 + kk * 32 + lg * 8];
#pragma unroll
                for (int rb = 0; rb < 2; ++rb)
                    acc[rb][nb] = MFMA16(Af[rb], B, acc[rb][nb]);
            }
        }
    }

#pragma unroll
    for (int rb = 0; rb < 2; ++rb)
#pragma unroll
        for (int nb = 0; nb < 8; ++nb)
#pragma unroll
            for (int r = 0; r < 4; ++r)
                op[(size_t)(w * 32 + rb * 16 + lg * 4 + r) * 16384 + pos0 + nb * 16 + lr] =
                    acc[rb][nb][r];
}

// ---------------------------------------------------------------------------
extern "C" void kernel_launch(void* const* d_in, const int* in_sizes, int n_in,
                              void* d_out, int out_size, void* d_ws, size_t ws_size,
                              hipStream_t stream) {
    const float* x    = (const float*)d_in[0];
    const float* skip = (const float*)d_in[1];
    const float* sinp = (const float*)d_in[2];
    const float* cosp = (const float*)d_in[3];
    const float* Wq   = (const float*)d_in[4];
    const float* Wkv  = (const float*)d_in[5];
    const float* Wout = (const float*)d_in[6];
    float* out = (float*)d_out;

    // workspace: qb 16.7M bf16 | kb 33.5M bf16 | vb 33.5M bf16  (160 MiB total)
    u16* qb = (u16*)d_ws;
    u16* kbp = qb + (size_t)16777216;
    u16* vbp = kbp + (size_t)33554432;

    hipLaunchKernelGGL(k_proj, dim3(128, 40), dim3(256), 0, stream,
                       x, skip, sinp, cosp, Wq, Wkv, qb, kbp, vbp);
    hipLaunchKernelGGL(k_attn, dim3(1024), dim3(256), 0, stream,
                       qb, kbp, vbp, qb /* in-place output over q */);
    hipLaunchKernelGGL(k_out, dim3(128, 2), dim3(256), 0, stream,
                       qb, Wout, out);
}

// Round 2
// 205.438 us; speedup vs baseline: 1.4175x; 1.4175x over previous
//
#include <hip/hip_runtime.h>
#include <hip/hip_bf16.h>

// LeWinAttention: q/kv projection + scrambled-reshape windowed attention + out projection.
// After the reference's raw reshapes, every attention batch b' uses CONTIGUOUS
// 256x64 (Q) / 512x64 (K,V) row-major bf16 tiles at offsets b'*16384 / 2*b'*16384,
// and writes its output back at b'*16384 in q's layout.

typedef unsigned short u16;
using bfrag = __attribute__((ext_vector_type(8))) short;   // 8 x bf16
using ffrag = __attribute__((ext_vector_type(4))) float;   // 4 x f32 accum

#define MFMA16(a, b, c) __builtin_amdgcn_mfma_f32_16x16x32_bf16((a), (b), (c), 0, 0, 0)

__device__ __forceinline__ u16 f2bf(float f) {
    __hip_bfloat16 h = __float2bfloat16(f);
    u16 u;
    __builtin_memcpy(&u, &h, 2);
    return u;
}

// bijective slot swizzle: distinct over {pos=base+lr} AND {pos=8k+e} patterns
__device__ __forceinline__ int sw(int p) { return (p ^ (p >> 3)) & 15; }

// ---------------------------------------------------------------------------
// Kernel 0: cast Wq (512x128), Wkv (1024x128), Wout (128x512) f32 -> bf16.
// WB = [Wq rows 0..511 | Wkv rows 512..1535], WoutB separate. 262144 elems.
// ---------------------------------------------------------------------------
__global__ __launch_bounds__(256) void k_prep(
    const float* __restrict__ Wq, const float* __restrict__ Wkv,
    const float* __restrict__ Wout, u16* __restrict__ WB, u16* __restrict__ WoutB)
{
    int i8 = (blockIdx.x * 256 + threadIdx.x) * 8;
    const float* src;
    u16* dst;
    if (i8 < 65536)       { src = Wq + i8;            dst = WB + i8; }
    else if (i8 < 196608) { src = Wkv + (i8 - 65536); dst = WB + i8; }
    else                  { src = Wout + (i8 - 196608); dst = WoutB + (i8 - 196608); }
    float4 a = *(const float4*)src;
    float4 b = *(const float4*)(src + 4);
    u16 tmp[8];
    tmp[0] = f2bf(a.x); tmp[1] = f2bf(a.y); tmp[2] = f2bf(a.z); tmp[3] = f2bf(a.w);
    tmp[4] = f2bf(b.x); tmp[5] = f2bf(b.y); tmp[6] = f2bf(b.z); tmp[7] = f2bf(b.w);
    *(uint4*)dst = *(uint4*)tmp;
}

// ---------------------------------------------------------------------------
// Kernel 1: transpose-cast x,skip f32 [c][pos] -> xb bf16 [plane][pos][c] linear.
// planes: 0,1 = x b0,b1 ; 2,3 = skip b0,b1. Tile [128 c][64 pos], LDS f32 pitch 65.
// ---------------------------------------------------------------------------
__global__ __launch_bounds__(256) void k_cast(
    const float* __restrict__ x, const float* __restrict__ skip,
    u16* __restrict__ xb)
{
    __shared__ float LT[128 * 65];
    const int t = threadIdx.x;
    const int pos0 = blockIdx.x * 64;
    const int p = blockIdx.y;
    const float* src = (p < 2) ? (x + (size_t)p * 2097152)
                               : (skip + (size_t)(p - 2) * 2097152);
    u16* dst = xb + (size_t)p * 2097152;

#pragma unroll
    for (int it = 0; it < 8; ++it) {
        int idx = it * 256 + t;
        int c = idx >> 4, p4 = (idx & 15) * 4;
        float4 v = *(const float4*)(src + (size_t)c * 16384 + pos0 + p4);
        LT[c * 65 + p4 + 0] = v.x;
        LT[c * 65 + p4 + 1] = v.y;
        LT[c * 65 + p4 + 2] = v.z;
        LT[c * 65 + p4 + 3] = v.w;
    }
    __syncthreads();

#pragma unroll
    for (int it = 0; it < 4; ++it) {
        int g = it * 256 + t;
        int pos_l = g >> 4, chunk = g & 15;
        u16 tmp[8];
#pragma unroll
        for (int j = 0; j < 8; ++j)
            tmp[j] = f2bf(LT[(chunk * 8 + j) * 65 + pos_l]);
        *(uint4*)(dst + (size_t)(pos0 + pos_l) * 128 + chunk * 8) = *(uint4*)tmp;
    }
}

// ---------------------------------------------------------------------------
// Kernel 2: projection GEMM (128 out-rows x 128 pos, K=128) + RoPE epilogue.
// grid = (128 pos-tiles, 40 row-tiles). A-frags b128 from WB (L2-hot).
// B staged reg->LDS with XOR swizzle (<=2-way banks). Epilogue: RoPE in regs,
// swizzled LDS repack, dwordx4 coalesced stores.
// ---------------------------------------------------------------------------
__global__ __launch_bounds__(256) void k_proj(
    const u16* __restrict__ xb, const float* __restrict__ sinp,
    const float* __restrict__ cosp, const u16* __restrict__ WB,
    u16* __restrict__ qb, u16* __restrict__ kbuf, u16* __restrict__ vbuf)
{
    __shared__ u16 BT[128 * 128];   // B-tile, then reused as output repack tile
    const int t = threadIdx.x;
    const int pos0 = blockIdx.x * 128;
    const int tr = blockIdx.y;
    const int w = t >> 6, l = t & 63, lr = l & 15, lg = l >> 4;
    const int wm = w >> 1, wn = w & 1;

    int WBrow, plane, mode;  // mode: 0 none (v), 1 q-rope, 2 k-rope
    u16* dst;
    if (tr < 8) {
        int b = tr >> 2, o0 = (tr & 3) * 128;
        WBrow = o0; plane = b; mode = 1;
        dst = qb + (size_t)b * 8388608 + (size_t)o0 * 16384;
    } else {
        int t2 = tr - 8;
        int bkv = t2 >> 3, oo0 = (t2 & 7) * 128;
        WBrow = 512 + oo0; plane = bkv;
        if (oo0 < 512) { dst = kbuf + (size_t)bkv * 8388608 + (size_t)oo0 * 16384; mode = 2; }
        else           { dst = vbuf + (size_t)bkv * 8388608 + (size_t)(oo0 - 512) * 16384; mode = 0; }
    }

    // stage B tile: xb [pos0..pos0+127][128 c] -> BT swizzled
    const u16* xsrc = xb + (size_t)plane * 2097152 + (size_t)pos0 * 128;
#pragma unroll
    for (int it = 0; it < 8; ++it) {
        int li = it * 256 + t;
        int row = li >> 4, chunk = li & 15;
        uint4 v = *(const uint4*)(xsrc + (size_t)row * 128 + chunk * 8);
        *(uint4*)&BT[row * 128 + ((chunk ^ sw(row)) << 3)] = v;
    }

    ffrag zf = {0.f, 0.f, 0.f, 0.f};
    ffrag acc[4][4];
#pragma unroll
    for (int rb = 0; rb < 4; ++rb)
#pragma unroll
        for (int nb = 0; nb < 4; ++nb) acc[rb][nb] = zf;

    __syncthreads();

#pragma unroll
    for (int kk = 0; kk < 4; ++kk) {
        bfrag A[4], B[4];
#pragma unroll
        for (int rb = 0; rb < 4; ++rb)
            A[rb] = *(const bfrag*)(WB + (size_t)(WBrow + wm * 64 + rb * 16 + lr) * 128 + kk * 32 + lg * 8);
#pragma unroll
        for (int nb = 0; nb < 4; ++nb) {
            int pos_l = wn * 64 + nb * 16 + lr;
            B[nb] = *(const bfrag*)&BT[pos_l * 128 + (((kk * 4 + lg) ^ sw(pos_l)) << 3)];
        }
#pragma unroll
        for (int rb = 0; rb < 4; ++rb)
#pragma unroll
            for (int nb = 0; nb < 4; ++nb)
                acc[rb][nb] = MFMA16(A[rb], B[nb], acc[rb][nb]);
    }

    __syncthreads();  // BT reuse as repack tile

    // epilogue: RoPE (exact reference semantics incl. the k "+cos" form),
    // write to swizzled LDS [row][pos]
#pragma unroll
    for (int rb = 0; rb < 4; ++rb)
#pragma unroll
        for (int nb = 0; nb < 4; ++nb) {
            int pos_l = wn * 64 + nb * 16 + lr;
            int posb = pos0 + pos_l;
            int hh = posb >> 7, ww = posb & 127, s = ww & 63;
            bool roped = (mode != 0) && (s < 32);
#pragma unroll
            for (int r = 0; r < 4; ++r) {
                int row = wm * 64 + rb * 16 + lg * 4 + r;
                float v = acc[rb][nb][r];
                if (roped) {
                    int pidx = (row & 63) * 2 + (hh >> 6);
                    int ridx = (hh & 63) * 2 + (ww >> 6);
                    int sidx = (pidx * 128 + ridx) * 32 + s;
                    float sv = sinp[sidx], cv = cosp[sidx];
                    float sg = (s & 1) ? sv : -sv;        // rotate_half: -even, +odd
                    v = (mode == 1) ? v * (cv + sg)       // q: q*cos + rot(q)*sin
                                    : v * (1.f + sg) + cv; // k: k + cos + rot(k)*sin
                }
                int slot = pos_l >> 3;
                BT[row * 128 + ((slot ^ (row & 15)) << 3) + (lr & 7)] = f2bf(v);
            }
        }

    __syncthreads();

    // coalesced store: 8 x dwordx4 per thread (each 16-lane group = 256B row)
#pragma unroll
    for (int it = 0; it < 8; ++it) {
        int g = it * 256 + t;
        int row = g >> 4, slot = g & 15;
        uint4 v = *(const uint4*)&BT[row * 128 + ((slot ^ (row & 15)) << 3)];
        *(uint4*)(dst + (size_t)row * 16384 + pos0 + slot * 8) = v;
    }
}

// ---------------------------------------------------------------------------
// Kernel 3: windowed attention (UNCHANGED from passing round-0 kernel).
// ---------------------------------------------------------------------------
__global__ __launch_bounds__(256) void k_attn(
    const u16* __restrict__ qb, const u16* __restrict__ kbuf,
    const u16* __restrict__ vbuf, u16* __restrict__ ob)
{
    __shared__ u16 Ks[64 * 72];
    __shared__ u16 Vt[64 * 72];
    __shared__ u16 Ps[4][64 * 72];
    const int bp = blockIdx.x;
    const int t = threadIdx.x, w = t >> 6, l = t & 63, lr = l & 15, lg = l >> 4;

    const u16* Qg = qb + (size_t)bp * 16384 + w * 4096;
    const u16* Kg = kbuf + (size_t)bp * 32768;
    const u16* Vg = vbuf + (size_t)bp * 32768;

    bfrag Qf[4][2];
#pragma unroll
    for (int rb = 0; rb < 4; ++rb)
#pragma unroll
        for (int kk = 0; kk < 2; ++kk)
            Qf[rb][kk] = *(const bfrag*)(Qg + (rb * 16 + lr) * 64 + kk * 32 + lg * 8);

    ffrag zf = {0.f, 0.f, 0.f, 0.f};
    ffrag Oacc[4][4];
    float Ls[4][4];
#pragma unroll
    for (int rb = 0; rb < 4; ++rb) {
#pragma unroll
        for (int sb = 0; sb < 4; ++sb) Oacc[rb][sb] = zf;
#pragma unroll
        for (int r = 0; r < 4; ++r) Ls[rb][r] = 0.f;
    }

    const int sj = t >> 2, ss0 = (t & 3) * 16;

    for (int c = 0; c < 8; ++c) {
        __syncthreads();
        {
            const u16* kc_ = Kg + c * 4096;
            uint4 k0 = *(const uint4*)(kc_ + sj * 64 + ss0);
            uint4 k1 = *(const uint4*)(kc_ + sj * 64 + ss0 + 8);
            *(uint4*)&Ks[sj * 72 + ss0] = k0;
            *(uint4*)&Ks[sj * 72 + ss0 + 8] = k1;
            const u16* vc_ = Vg + c * 4096;
            uint4 v0 = *(const uint4*)(vc_ + sj * 64 + ss0);
            uint4 v1 = *(const uint4*)(vc_ + sj * 64 + ss0 + 8);
            u16 tmp[16];
            *(uint4*)&tmp[0] = v0;
            *(uint4*)&tmp[8] = v1;
#pragma unroll
            for (int e = 0; e < 16; ++e)
                Vt[(ss0 + e) * 72 + sj] = tmp[e];
        }
        __syncthreads();

        bfrag Bf[2][4];
#pragma unroll
        for (int kk = 0; kk < 2; ++kk)
#pragma unroll
            for (int cb = 0; cb < 4; ++cb)
                Bf[kk][cb] = *(const bfrag*)&Ks[(cb * 16 + lr) * 72 + kk * 32 + lg * 8];

#pragma unroll
        for (int rb = 0; rb < 4; ++rb) {
            float rsum[4] = {0.f, 0.f, 0.f, 0.f};
#pragma unroll
            for (int cb = 0; cb < 4; ++cb) {
                ffrag sf = zf;
                sf = MFMA16(Qf[rb][0], Bf[0][cb], sf);
                sf = MFMA16(Qf[rb][1], Bf[1][cb], sf);
#pragma unroll
                for (int r = 0; r < 4; ++r) {
                    float e = __expf(sf[r] * 0.125f);
                    rsum[r] += e;
                    Ps[w][(rb * 16 + lg * 4 + r) * 72 + cb * 16 + lr] = f2bf(e);
                }
            }
#pragma unroll
            for (int r = 0; r < 4; ++r) {
                float v = rsum[r];
                v += __shfl_xor(v, 1);
                v += __shfl_xor(v, 2);
                v += __shfl_xor(v, 4);
                v += __shfl_xor(v, 8);
                Ls[rb][r] += v;
            }
        }

#pragma unroll
        for (int kk = 0; kk < 2; ++kk) {
            bfrag Vf[4];
#pragma unroll
            for (int sb = 0; sb < 4; ++sb)
                Vf[sb] = *(const bfrag*)&Vt[(sb * 16 + lr) * 72 + kk * 32 + lg * 8];
#pragma unroll
            for (int rb = 0; rb < 4; ++rb) {
                bfrag Pf = *(const bfrag*)&Ps[w][(rb * 16 + lr) * 72 + kk * 32 + lg * 8];
#pragma unroll
                for (int sb = 0; sb < 4; ++sb)
                    Oacc[rb][sb] = MFMA16(Pf, Vf[sb], Oacc[rb][sb]);
            }
        }
    }

    u16* og = ob + (size_t)bp * 16384 + w * 4096;
#pragma unroll
    for (int rb = 0; rb < 4; ++rb) {
        float inv[4];
#pragma unroll
        for (int r = 0; r < 4; ++r) inv[r] = 1.f / Ls[rb][r];
#pragma unroll
        for (int sb = 0; sb < 4; ++sb)
#pragma unroll
            for (int r = 0; r < 4; ++r)
                og[(rb * 16 + lg * 4 + r) * 64 + sb * 16 + lr] =
                    f2bf(Oacc[rb][sb][r] * inv[r]);
    }
}

// ---------------------------------------------------------------------------
// Kernel 4: out projection out[b][o2][pos] = sum_c2 WoutB[o2][c2]*ob[b][c2][pos].
// grid (256 pos-tiles of 64, 2 b). Swizzled LDS staging, A b128 from WoutB.
// ---------------------------------------------------------------------------
__global__ __launch_bounds__(256) void k_out(
    const u16* __restrict__ ob, const u16* __restrict__ WoutB,
    float* __restrict__ out)
{
    __shared__ u16 OT[64 * 128];   // [pos_l][c2 chunk swizzled]
    const int t = threadIdx.x, w = t >> 6, l = t & 63, lr = l & 15, lg = l >> 4;
    const int pos0 = blockIdx.x * 64;
    const int b = blockIdx.y;
    const u16* obp = ob + (size_t)b * 8388608;
    float* op = out + (size_t)b * 2097152;

    ffrag zf = {0.f, 0.f, 0.f, 0.f};
    ffrag acc[2][4];
#pragma unroll
    for (int rb = 0; rb < 2; ++rb)
#pragma unroll
        for (int nb = 0; nb < 4; ++nb) acc[rb][nb] = zf;

    for (int kc = 0; kc < 4; ++kc) {
        __syncthreads();
        // stage [64 pos][128 c2-local]: load along pos (coalesced), scatter swizzled
#pragma unroll
        for (int it = 0; it < 4; ++it) {
            int g = it * 256 + t;
            int cl = g >> 3, pk = g & 7;
            uint4 v = *(const uint4*)(obp + (size_t)(kc * 128 + cl) * 16384 + pos0 + pk * 8);
            u16 tmp[8];
            *(uint4*)tmp = v;
#pragma unroll
            for (int e = 0; e < 8; ++e) {
                int pos_l = pk * 8 + e;
                OT[pos_l * 128 + (((cl >> 3) ^ sw(pos_l)) << 3) + (cl & 7)] = tmp[e];
            }
        }
        __syncthreads();

#pragma unroll
        for (int kk = 0; kk < 4; ++kk) {
            bfrag Af[2];
#pragma unroll
            for (int rb = 0; rb < 2; ++rb)
                Af[rb] = *(const bfrag*)(WoutB + (size_t)(w * 32 + rb * 16 + lr) * 512 + kc * 128 + kk * 32 + lg * 8);
#pragma unroll
            for (int nb = 0; nb < 4; ++nb) {
                int pos_l = nb * 16 + lr;
                bfrag B = *(const bfrag*)&OT[pos_l * 128 + (((kk * 4 + lg) ^ sw(pos_l)) << 3)];
#pragma unroll
                for (int rb = 0; rb < 2; ++rb)
                    acc[rb][nb] = MFMA16(Af[rb], B, acc[rb][nb]);
            }
        }
    }

#pragma unroll
    for (int rb = 0; rb < 2; ++rb)
#pragma unroll
        for (int nb = 0; nb < 4; ++nb)
#pragma unroll
            for (int r = 0; r < 4; ++r)
                op[(size_t)(w * 32 + rb * 16 + lg * 4 + r) * 16384 + pos0 + nb * 16 + lr] =
                    acc[rb][nb][r];
}

// ---------------------------------------------------------------------------
extern "C" void kernel_launch(void* const* d_in, const int* in_sizes, int n_in,
                              void* d_out, int out_size, void* d_ws, size_t ws_size,
                              hipStream_t stream) {
    const float* x    = (const float*)d_in[0];
    const float* skip = (const float*)d_in[1];
    const float* sinp = (const float*)d_in[2];
    const float* cosp = (const float*)d_in[3];
    const float* Wq   = (const float*)d_in[4];
    const float* Wkv  = (const float*)d_in[5];
    const float* Wout = (const float*)d_in[6];
    float* out = (float*)d_out;

    // workspace (u16 units): qb 16.7M | kbuf 33.5M | vbuf 33.5M | xb 8.4M | WB | WoutB
    u16* qb    = (u16*)d_ws;
    u16* kbp   = qb + (size_t)16777216;
    u16* vbp   = kbp + (size_t)33554432;
    u16* xbp   = vbp + (size_t)33554432;
    u16* WBp   = xbp + (size_t)8388608;
    u16* WoutB = WBp + (size_t)196608;

    hipLaunchKernelGGL(k_prep, dim3(128), dim3(256), 0, stream,
                       Wq, Wkv, Wout, WBp, WoutB);
    hipLaunchKernelGGL(k_cast, dim3(256, 4), dim3(256), 0, stream,
                       x, skip, xbp);
    hipLaunchKernelGGL(k_proj, dim3(128, 40), dim3(256), 0, stream,
                       xbp, sinp, cosp, WBp, qb, kbp, vbp);
    hipLaunchKernelGGL(k_attn, dim3(1024), dim3(256), 0, stream,
                       qb, kbp, vbp, qb /* in-place output over q */);
    hipLaunchKernelGGL(k_out, dim3(256, 2), dim3(256), 0, stream,
                       qb, WoutB, out);
}

// Round 4
// 180.240 us; speedup vs baseline: 1.6157x; 1.1398x over previous
//
#include <hip/hip_runtime.h>
#include <hip/hip_bf16.h>

// LeWinAttention: q/kv projection + scrambled-reshape windowed attention + out projection.
// After the reference's raw reshapes, every attention batch b' uses CONTIGUOUS
// 256x64 (Q) / 512x64 (K,V) row-major bf16 tiles at offsets b'*16384 / 2*b'*16384,
// and writes its output back at b'*16384 in q's layout.

typedef unsigned short u16;
using bfrag = __attribute__((ext_vector_type(8))) short;   // 8 x bf16
using ffrag = __attribute__((ext_vector_type(4))) float;   // 4 x f32 accum
using s4v   = __attribute__((ext_vector_type(4))) short;   // 4 x bf16

#define MFMA16(a, b, c) __builtin_amdgcn_mfma_f32_16x16x32_bf16((a), (b), (c), 0, 0, 0)

__device__ __forceinline__ u16 f2bf(float f) {
    __hip_bfloat16 h = __float2bfloat16(f);
    u16 u;
    __builtin_memcpy(&u, &h, 2);
    return u;
}

// bijective slot swizzle: distinct over {pos=base+lr} AND {pos=8k+e} patterns
__device__ __forceinline__ int sw(int p) { return (p ^ (p >> 3)) & 15; }

// ---------------------------------------------------------------------------
// Kernel 0: cast Wq (512x128), Wkv (1024x128), Wout (128x512) f32 -> bf16.
// ---------------------------------------------------------------------------
__global__ __launch_bounds__(256) void k_prep(
    const float* __restrict__ Wq, const float* __restrict__ Wkv,
    const float* __restrict__ Wout, u16* __restrict__ WB, u16* __restrict__ WoutB)
{
    int i8 = (blockIdx.x * 256 + threadIdx.x) * 8;
    const float* src;
    u16* dst;
    if (i8 < 65536)       { src = Wq + i8;            dst = WB + i8; }
    else if (i8 < 196608) { src = Wkv + (i8 - 65536); dst = WB + i8; }
    else                  { src = Wout + (i8 - 196608); dst = WoutB + (i8 - 196608); }
    float4 a = *(const float4*)src;
    float4 b = *(const float4*)(src + 4);
    u16 tmp[8];
    tmp[0] = f2bf(a.x); tmp[1] = f2bf(a.y); tmp[2] = f2bf(a.z); tmp[3] = f2bf(a.w);
    tmp[4] = f2bf(b.x); tmp[5] = f2bf(b.y); tmp[6] = f2bf(b.z); tmp[7] = f2bf(b.w);
    *(uint4*)dst = *(uint4*)tmp;
}

// ---------------------------------------------------------------------------
// Kernel 1: transpose-cast x,skip f32 [c][pos] -> xb bf16 [plane][pos][c] linear.
// ---------------------------------------------------------------------------
__global__ __launch_bounds__(256) void k_cast(
    const float* __restrict__ x, const float* __restrict__ skip,
    u16* __restrict__ xb)
{
    __shared__ float LT[128 * 65];
    const int t = threadIdx.x;
    const int pos0 = blockIdx.x * 64;
    const int p = blockIdx.y;
    const float* src = (p < 2) ? (x + (size_t)p * 2097152)
                               : (skip + (size_t)(p - 2) * 2097152);
    u16* dst = xb + (size_t)p * 2097152;

#pragma unroll
    for (int it = 0; it < 8; ++it) {
        int idx = it * 256 + t;
        int c = idx >> 4, p4 = (idx & 15) * 4;
        float4 v = *(const float4*)(src + (size_t)c * 16384 + pos0 + p4);
        LT[c * 65 + p4 + 0] = v.x;
        LT[c * 65 + p4 + 1] = v.y;
        LT[c * 65 + p4 + 2] = v.z;
        LT[c * 65 + p4 + 3] = v.w;
    }
    __syncthreads();

#pragma unroll
    for (int it = 0; it < 4; ++it) {
        int g = it * 256 + t;
        int pos_l = g >> 4, chunk = g & 15;
        u16 tmp[8];
#pragma unroll
        for (int j = 0; j < 8; ++j)
            tmp[j] = f2bf(LT[(chunk * 8 + j) * 65 + pos_l]);
        *(uint4*)(dst + (size_t)(pos0 + pos_l) * 128 + chunk * 8) = *(uint4*)tmp;
    }
}

// ---------------------------------------------------------------------------
// Kernel 2: projection GEMM (128 out-rows x 128 pos, K=128) + RoPE epilogue.
// ---------------------------------------------------------------------------
__global__ __launch_bounds__(256) void k_proj(
    const u16* __restrict__ xb, const float* __restrict__ sinp,
    const float* __restrict__ cosp, const u16* __restrict__ WB,
    u16* __restrict__ qb, u16* __restrict__ kbuf, u16* __restrict__ vbuf)
{
    __shared__ u16 BT[128 * 128];   // B-tile, then reused as output repack tile
    const int t = threadIdx.x;
    const int pos0 = blockIdx.x * 128;
    const int tr = blockIdx.y;
    const int w = t >> 6, l = t & 63, lr = l & 15, lg = l >> 4;
    const int wm = w >> 1, wn = w & 1;

    int WBrow, plane, mode;  // mode: 0 none (v), 1 q-rope, 2 k-rope
    u16* dst;
    if (tr < 8) {
        int b = tr >> 2, o0 = (tr & 3) * 128;
        WBrow = o0; plane = b; mode = 1;
        dst = qb + (size_t)b * 8388608 + (size_t)o0 * 16384;
    } else {
        int t2 = tr - 8;
        int bkv = t2 >> 3, oo0 = (t2 & 7) * 128;
        WBrow = 512 + oo0; plane = bkv;
        if (oo0 < 512) { dst = kbuf + (size_t)bkv * 8388608 + (size_t)oo0 * 16384; mode = 2; }
        else           { dst = vbuf + (size_t)bkv * 8388608 + (size_t)(oo0 - 512) * 16384; mode = 0; }
    }

    const u16* xsrc = xb + (size_t)plane * 2097152 + (size_t)pos0 * 128;
#pragma unroll
    for (int it = 0; it < 8; ++it) {
        int li = it * 256 + t;
        int row = li >> 4, chunk = li & 15;
        uint4 v = *(const uint4*)(xsrc + (size_t)row * 128 + chunk * 8);
        *(uint4*)&BT[row * 128 + ((chunk ^ sw(row)) << 3)] = v;
    }

    ffrag zf = {0.f, 0.f, 0.f, 0.f};
    ffrag acc[4][4];
#pragma unroll
    for (int rb = 0; rb < 4; ++rb)
#pragma unroll
        for (int nb = 0; nb < 4; ++nb) acc[rb][nb] = zf;

    __syncthreads();

#pragma unroll
    for (int kk = 0; kk < 4; ++kk) {
        bfrag A[4], B[4];
#pragma unroll
        for (int rb = 0; rb < 4; ++rb)
            A[rb] = *(const bfrag*)(WB + (size_t)(WBrow + wm * 64 + rb * 16 + lr) * 128 + kk * 32 + lg * 8);
#pragma unroll
        for (int nb = 0; nb < 4; ++nb) {
            int pos_l = wn * 64 + nb * 16 + lr;
            B[nb] = *(const bfrag*)&BT[pos_l * 128 + (((kk * 4 + lg) ^ sw(pos_l)) << 3)];
        }
#pragma unroll
        for (int rb = 0; rb < 4; ++rb)
#pragma unroll
            for (int nb = 0; nb < 4; ++nb)
                acc[rb][nb] = MFMA16(A[rb], B[nb], acc[rb][nb]);
    }

    __syncthreads();  // BT reuse as repack tile

#pragma unroll
    for (int rb = 0; rb < 4; ++rb)
#pragma unroll
        for (int nb = 0; nb < 4; ++nb) {
            int pos_l = wn * 64 + nb * 16 + lr;
            int posb = pos0 + pos_l;
            int hh = posb >> 7, ww = posb & 127, s = ww & 63;
            bool roped = (mode != 0) && (s < 32);
#pragma unroll
            for (int r = 0; r < 4; ++r) {
                int row = wm * 64 + rb * 16 + lg * 4 + r;
                float v = acc[rb][nb][r];
                if (roped) {
                    int pidx = (row & 63) * 2 + (hh >> 6);
                    int ridx = (hh & 63) * 2 + (ww >> 6);
                    int sidx = (pidx * 128 + ridx) * 32 + s;
                    float sv = sinp[sidx], cv = cosp[sidx];
                    float sg = (s & 1) ? sv : -sv;        // rotate_half: -even, +odd
                    v = (mode == 1) ? v * (cv + sg)       // q: q*cos + rot(q)*sin
                                    : v * (1.f + sg) + cv; // k: k + cos + rot(k)*sin
                }
                int slot = pos_l >> 3;
                BT[row * 128 + ((slot ^ (row & 15)) << 3) + (lr & 7)] = f2bf(v);
            }
        }

    __syncthreads();

#pragma unroll
    for (int it = 0; it < 8; ++it) {
        int g = it * 256 + t;
        int row = g >> 4, slot = g & 15;
        uint4 v = *(const uint4*)&BT[row * 128 + ((slot ^ (row & 15)) << 3)];
        *(uint4*)(dst + (size_t)row * 16384 + pos0 + slot * 8) = v;
    }
}

// ---------------------------------------------------------------------------
// Kernel 3: windowed attention. 1024 batches, 8 waves x 32 q-rows per block.
// Swapped QK^T (A=K, B=Q): lane holds S^T frag -> packed b64 P-store +
// lane-local row-sums. V staged TRANSPOSED into Vt[d][j] (scalar writes,
// bank-spread XOR swizzle) so the PV B-frag is a plain swizzled ds_read_b128.
// No inline asm. Output written IN-PLACE over the q buffer (disjoint/block).
// ---------------------------------------------------------------------------
__global__ __launch_bounds__(512, 4) void k_attn(
    const u16* __restrict__ qb, const u16* __restrict__ kbuf,
    const u16* __restrict__ vbuf, u16* __restrict__ ob)
{
    __shared__ u16 Ks[64 * 64];      // [j][d-chunk ^ (j&7)]
    __shared__ u16 Vt[64 * 64];      // [d][j-chunk ^ s(d)], s(d)=(d&7)^((d>>3)&7)
    __shared__ u16 Ps[8][32 * 40];   // per wave: [i_local][j-half 32, pitch 40]
    __shared__ float Lbuf[256];

    const int bp = blockIdx.x;
    const int t = threadIdx.x, w = t >> 6, l = t & 63, lr = l & 15, lg = l >> 4;

    const u16* Qg = qb + (size_t)bp * 16384 + w * 2048;   // wave's 32 q-rows
    const u16* Kg = kbuf + (size_t)bp * 32768;
    const u16* Vg = vbuf + (size_t)bp * 32768;

    // Q as B-frags (col = i = lr, k = d = lg*8+e)
    bfrag Qf[2][2];
#pragma unroll
    for (int rb = 0; rb < 2; ++rb)
#pragma unroll
        for (int dk = 0; dk < 2; ++dk)
            Qf[rb][dk] = *(const bfrag*)(Qg + (rb * 16 + lr) * 64 + dk * 32 + lg * 8);

    ffrag zf = {0.f, 0.f, 0.f, 0.f};
    ffrag Oacc[2][4];
#pragma unroll
    for (int rb = 0; rb < 2; ++rb)
#pragma unroll
        for (int sb = 0; sb < 4; ++sb) Oacc[rb][sb] = zf;
    float Lp[2] = {0.f, 0.f};

    // staging: threads 0..255 stage K, 256..511 stage V (32B each per chunk)
    const int t2 = t & 255, sj = t2 >> 2, sq = t2 & 3;
    const bool isK = (t < 256);
    const u16* gs = (isK ? Kg : Vg) + sj * 64 + sq * 16;

    uint4 r0 = *(const uint4*)gs;              // prefetch chunk 0
    uint4 r1 = *(const uint4*)(gs + 8);

    for (int c = 0; c < 8; ++c) {
        __syncthreads();                       // prev chunk's readers done
        if (isK) {
            *(uint4*)&Ks[sj * 64 + (((sq * 2) ^ (sj & 7)) << 3)] = r0;
            *(uint4*)&Ks[sj * 64 + (((sq * 2 + 1) ^ (sj & 7)) << 3)] = r1;
        } else {
            u16 tmp[16];
            *(uint4*)&tmp[0] = r0;
            *(uint4*)&tmp[8] = r1;
            const int chunk = sj >> 3, jl = sj & 7;
#pragma unroll
            for (int e = 0; e < 16; ++e) {
                int d = sq * 16 + e;
                int s = (d & 7) ^ ((d >> 3) & 7);
                Vt[d * 64 + ((chunk ^ s) << 3) + jl] = tmp[e];   // V^T[d][j]
            }
        }
        __syncthreads();                       // tiles visible
        if (c < 7) {                           // prefetch next chunk (overlaps compute)
            r0 = *(const uint4*)(gs + (c + 1) * 4096);
            r1 = *(const uint4*)(gs + (c + 1) * 4096 + 8);
        }

#pragma unroll
        for (int jh = 0; jh < 2; ++jh) {
            // --- S^T tiles + exp + packed P-store for this 32-j half ---
#pragma unroll
            for (int jtl = 0; jtl < 2; ++jtl) {
                const int jt = jh * 2 + jtl;
                bfrag Kf[2];
#pragma unroll
                for (int dk = 0; dk < 2; ++dk)
                    Kf[dk] = *(const bfrag*)&Ks[(jt * 16 + lr) * 64 + (((dk * 4 + lg) ^ (lr & 7)) << 3)];
#pragma unroll
                for (int rb = 0; rb < 2; ++rb) {
                    ffrag sf = zf;
                    sf = MFMA16(Kf[0], Qf[rb][0], sf);   // D[j_loc=lg*4+r][i_loc=lr]
                    sf = MFMA16(Kf[1], Qf[rb][1], sf);
                    float e0 = __expf(sf[0] * 0.125f);   // SCALE = 1/sqrt(64)
                    float e1 = __expf(sf[1] * 0.125f);
                    float e2 = __expf(sf[2] * 0.125f);
                    float e3 = __expf(sf[3] * 0.125f);
                    Lp[rb] += (e0 + e1) + (e2 + e3);
                    s4v pk;
                    pk[0] = (short)f2bf(e0); pk[1] = (short)f2bf(e1);
                    pk[2] = (short)f2bf(e2); pk[3] = (short)f2bf(e3);
                    *(s4v*)&Ps[w][(rb * 16 + lr) * 40 + jtl * 16 + lg * 4] = pk;
                }
            }

            // --- PV for this half: Vf = V^T rows, plain swizzled b128 reads ---
            bfrag Vf[4];
#pragma unroll
            for (int sb = 0; sb < 4; ++sb) {
                int d = sb * 16 + lr;
                int s = (d & 7) ^ ((d >> 3) & 7);
                Vf[sb] = *(const bfrag*)&Vt[d * 64 + (((jh * 4 + lg) ^ s) << 3)];
            }
#pragma unroll
            for (int rb = 0; rb < 2; ++rb) {
                bfrag Pf = *(const bfrag*)&Ps[w][(rb * 16 + lr) * 40 + lg * 8];
#pragma unroll
                for (int sb = 0; sb < 4; ++sb)
                    Oacc[rb][sb] = MFMA16(Pf, Vf[sb], Oacc[rb][sb]);  // D[i=lg*4+r][d=lr]
            }
        }
    }

    // finalize row sums (lane-local partials across lg groups) and broadcast via LDS
#pragma unroll
    for (int rb = 0; rb < 2; ++rb) {
        float v = Lp[rb];
        v += __shfl_xor(v, 16);
        v += __shfl_xor(v, 32);
        if (lg == 0) Lbuf[w * 32 + rb * 16 + lr] = v;
    }
    // same-wave producer/consumer: no barrier needed
    u16* og = ob + (size_t)bp * 16384 + w * 2048;
#pragma unroll
    for (int rb = 0; rb < 2; ++rb)
#pragma unroll
        for (int r = 0; r < 4; ++r) {
            float inv = 1.f / Lbuf[w * 32 + rb * 16 + lg * 4 + r];
#pragma unroll
            for (int sb = 0; sb < 4; ++sb)
                og[(rb * 16 + lg * 4 + r) * 64 + sb * 16 + lr] = f2bf(Oacc[rb][sb][r] * inv);
        }
}

// ---------------------------------------------------------------------------
// Kernel 4: out projection out[b][o2][pos] = sum_c2 WoutB[o2][c2]*ob[b][c2][pos].
// ---------------------------------------------------------------------------
__global__ __launch_bounds__(256) void k_out(
    const u16* __restrict__ ob, const u16* __restrict__ WoutB,
    float* __restrict__ out)
{
    __shared__ u16 OT[64 * 128];
    const int t = threadIdx.x, w = t >> 6, l = t & 63, lr = l & 15, lg = l >> 4;
    const int pos0 = blockIdx.x * 64;
    const int b = blockIdx.y;
    const u16* obp = ob + (size_t)b * 8388608;
    float* op = out + (size_t)b * 2097152;

    ffrag zf = {0.f, 0.f, 0.f, 0.f};
    ffrag acc[2][4];
#pragma unroll
    for (int rb = 0; rb < 2; ++rb)
#pragma unroll
        for (int nb = 0; nb < 4; ++nb) acc[rb][nb] = zf;

    for (int kc = 0; kc < 4; ++kc) {
        __syncthreads();
#pragma unroll
        for (int it = 0; it < 4; ++it) {
            int g = it * 256 + t;
            int cl = g >> 3, pk = g & 7;
            uint4 v = *(const uint4*)(obp + (size_t)(kc * 128 + cl) * 16384 + pos0 + pk * 8);
            u16 tmp[8];
            *(uint4*)tmp = v;
#pragma unroll
            for (int e = 0; e < 8; ++e) {
                int pos_l = pk * 8 + e;
                OT[pos_l * 128 + (((cl >> 3) ^ sw(pos_l)) << 3) + (cl & 7)] = tmp[e];
            }
        }
        __syncthreads();

#pragma unroll
        for (int kk = 0; kk < 4; ++kk) {
            bfrag Af[2];
#pragma unroll
            for (int rb = 0; rb < 2; ++rb)
                Af[rb] = *(const bfrag*)(WoutB + (size_t)(w * 32 + rb * 16 + lr) * 512 + kc * 128 + kk * 32 + lg * 8);
#pragma unroll
            for (int nb = 0; nb < 4; ++nb) {
                int pos_l = nb * 16 + lr;
                bfrag B = *(const bfrag*)&OT[pos_l * 128 + (((kk * 4 + lg) ^ sw(pos_l)) << 3)];
#pragma unroll
                for (int rb = 0; rb < 2; ++rb)
                    acc[rb][nb] = MFMA16(Af[rb], B, acc[rb][nb]);
            }
        }
    }

#pragma unroll
    for (int rb = 0; rb < 2; ++rb)
#pragma unroll
        for (int nb = 0; nb < 4; ++nb)
#pragma unroll
            for (int r = 0; r < 4; ++r)
                op[(size_t)(w * 32 + rb * 16 + lg * 4 + r) * 16384 + pos0 + nb * 16 + lr] =
                    acc[rb][nb][r];
}

// ---------------------------------------------------------------------------
extern "C" void kernel_launch(void* const* d_in, const int* in_sizes, int n_in,
                              void* d_out, int out_size, void* d_ws, size_t ws_size,
                              hipStream_t stream) {
    const float* x    = (const float*)d_in[0];
    const float* skip = (const float*)d_in[1];
    const float* sinp = (const float*)d_in[2];
    const float* cosp = (const float*)d_in[3];
    const float* Wq   = (const float*)d_in[4];
    const float* Wkv  = (const float*)d_in[5];
    const float* Wout = (const float*)d_in[6];
    float* out = (float*)d_out;

    // workspace (u16 units): qb 16.7M | kbuf 33.5M | vbuf 33.5M | xb 8.4M | WB | WoutB
    u16* qb    = (u16*)d_ws;
    u16* kbp   = qb + (size_t)16777216;
    u16* vbp   = kbp + (size_t)33554432;
    u16* xbp   = vbp + (size_t)33554432;
    u16* WBp   = xbp + (size_t)8388608;
    u16* WoutB = WBp + (size_t)196608;

    hipLaunchKernelGGL(k_prep, dim3(128), dim3(256), 0, stream,
                       Wq, Wkv, Wout, WBp, WoutB);
    hipLaunchKernelGGL(k_cast, dim3(256, 4), dim3(256), 0, stream,
                       x, skip, xbp);
    hipLaunchKernelGGL(k_proj, dim3(128, 40), dim3(256), 0, stream,
                       xbp, sinp, cosp, WBp, qb, kbp, vbp);
    hipLaunchKernelGGL(k_attn, dim3(1024), dim3(512), 0, stream,
                       qb, kbp, vbp, qb /* in-place output over q */);
    hipLaunchKernelGGL(k_out, dim3(256, 2), dim3(256), 0, stream,
                       qb, WoutB, out);
}

// Round 5
// 169.049 us; speedup vs baseline: 1.7226x; 1.0662x over previous
//
#include <hip/hip_runtime.h>
#include <hip/hip_bf16.h>

// LeWinAttention: q/kv projection + scrambled-reshape windowed attention + out projection.
// After the reference's raw reshapes, every attention batch b' uses CONTIGUOUS
// 256x64 (Q) / 512x64 (K,V) row-major bf16 tiles at offsets b'*16384 / 2*b'*16384,
// and writes its output back at b'*16384 in q's layout.

typedef unsigned short u16;
using bfrag = __attribute__((ext_vector_type(8))) short;   // 8 x bf16
using ffrag = __attribute__((ext_vector_type(4))) float;   // 4 x f32 accum
using s4v   = __attribute__((ext_vector_type(4))) short;   // 4 x bf16 (8B)

#define MFMA16(a, b, c) __builtin_amdgcn_mfma_f32_16x16x32_bf16((a), (b), (c), 0, 0, 0)

__device__ __forceinline__ u16 f2bf(float f) {
    __hip_bfloat16 h = __float2bfloat16(f);
    u16 u;
    __builtin_memcpy(&u, &h, 2);
    return u;
}

// bijective slot swizzle: distinct over {pos=base+lr} AND {pos=8k+e} patterns
__device__ __forceinline__ int sw(int p) { return (p ^ (p >> 3)) & 15; }

// ---------------------------------------------------------------------------
// Kernel 0: cast Wq (512x128), Wkv (1024x128), Wout (128x512) f32 -> bf16.
// ---------------------------------------------------------------------------
__global__ __launch_bounds__(256) void k_prep(
    const float* __restrict__ Wq, const float* __restrict__ Wkv,
    const float* __restrict__ Wout, u16* __restrict__ WB, u16* __restrict__ WoutB)
{
    int i8 = (blockIdx.x * 256 + threadIdx.x) * 8;
    const float* src;
    u16* dst;
    if (i8 < 65536)       { src = Wq + i8;            dst = WB + i8; }
    else if (i8 < 196608) { src = Wkv + (i8 - 65536); dst = WB + i8; }
    else                  { src = Wout + (i8 - 196608); dst = WoutB + (i8 - 196608); }
    float4 a = *(const float4*)src;
    float4 b = *(const float4*)(src + 4);
    u16 tmp[8];
    tmp[0] = f2bf(a.x); tmp[1] = f2bf(a.y); tmp[2] = f2bf(a.z); tmp[3] = f2bf(a.w);
    tmp[4] = f2bf(b.x); tmp[5] = f2bf(b.y); tmp[6] = f2bf(b.z); tmp[7] = f2bf(b.w);
    *(uint4*)dst = *(uint4*)tmp;
}

// ---------------------------------------------------------------------------
// Kernel 1: transpose-cast x,skip f32 [c][pos] -> xb bf16 [plane][pos][c] linear.
// ---------------------------------------------------------------------------
__global__ __launch_bounds__(256) void k_cast(
    const float* __restrict__ x, const float* __restrict__ skip,
    u16* __restrict__ xb)
{
    __shared__ float LT[128 * 65];
    const int t = threadIdx.x;
    const int pos0 = blockIdx.x * 64;
    const int p = blockIdx.y;
    const float* src = (p < 2) ? (x + (size_t)p * 2097152)
                               : (skip + (size_t)(p - 2) * 2097152);
    u16* dst = xb + (size_t)p * 2097152;

#pragma unroll
    for (int it = 0; it < 8; ++it) {
        int idx = it * 256 + t;
        int c = idx >> 4, p4 = (idx & 15) * 4;
        float4 v = *(const float4*)(src + (size_t)c * 16384 + pos0 + p4);
        LT[c * 65 + p4 + 0] = v.x;
        LT[c * 65 + p4 + 1] = v.y;
        LT[c * 65 + p4 + 2] = v.z;
        LT[c * 65 + p4 + 3] = v.w;
    }
    __syncthreads();

#pragma unroll
    for (int it = 0; it < 4; ++it) {
        int g = it * 256 + t;
        int pos_l = g >> 4, chunk = g & 15;
        u16 tmp[8];
#pragma unroll
        for (int j = 0; j < 8; ++j)
            tmp[j] = f2bf(LT[(chunk * 8 + j) * 65 + pos_l]);
        *(uint4*)(dst + (size_t)(pos0 + pos_l) * 128 + chunk * 8) = *(uint4*)tmp;
    }
}

// ---------------------------------------------------------------------------
// Kernel 2: projection GEMM + RoPE epilogue, operand-swapped:
// A = x-tile (rows = pos, from swizzled LDS), B = W (cols = o, b128 from WB).
// Acc: D[row = pos (register quad), col = o (lane)] -> RoPE branch uniform,
// float4 sin/cos loads, b64 LDS repack writes. grid = (128 pos-tiles, 40 row-tiles).
// ---------------------------------------------------------------------------
__global__ __launch_bounds__(256, 4) void k_proj(
    const u16* __restrict__ xb, const float* __restrict__ sinp,
    const float* __restrict__ cosp, const u16* __restrict__ WB,
    u16* __restrict__ qb, u16* __restrict__ kbuf, u16* __restrict__ vbuf)
{
    __shared__ u16 BT[128 * 128];   // x-tile, then reused as output repack tile
    const int t = threadIdx.x;
    const int pos0 = blockIdx.x * 128;
    const int tr = blockIdx.y;
    const int w = t >> 6, l = t & 63, lr = l & 15, lg = l >> 4;
    const int wp = w >> 1, wo = w & 1;   // wave -> 64-pos x 64-o quadrant

    int WBrow, plane, mode;  // mode: 0 none (v), 1 q-rope, 2 k-rope
    u16* dst;
    if (tr < 8) {
        int b = tr >> 2, o0 = (tr & 3) * 128;
        WBrow = o0; plane = b; mode = 1;
        dst = qb + (size_t)b * 8388608 + (size_t)o0 * 16384;
    } else {
        int t2 = tr - 8;
        int bkv = t2 >> 3, oo0 = (t2 & 7) * 128;
        WBrow = 512 + oo0; plane = bkv;
        if (oo0 < 512) { dst = kbuf + (size_t)bkv * 8388608 + (size_t)oo0 * 16384; mode = 2; }
        else           { dst = vbuf + (size_t)bkv * 8388608 + (size_t)(oo0 - 512) * 16384; mode = 0; }
    }

    // stage x tile: xb [pos0..pos0+127][128 c] -> BT swizzled
    const u16* xsrc = xb + (size_t)plane * 2097152 + (size_t)pos0 * 128;
#pragma unroll
    for (int it = 0; it < 8; ++it) {
        int li = it * 256 + t;
        int row = li >> 4, chunk = li & 15;
        uint4 v = *(const uint4*)(xsrc + (size_t)row * 128 + chunk * 8);
        *(uint4*)&BT[row * 128 + ((chunk ^ sw(row)) << 3)] = v;
    }

    ffrag zf = {0.f, 0.f, 0.f, 0.f};
    ffrag acc[4][4];   // [mb = pos 16-block][nb = o 16-block]
#pragma unroll
    for (int mb = 0; mb < 4; ++mb)
#pragma unroll
        for (int nb = 0; nb < 4; ++nb) acc[mb][nb] = zf;

    __syncthreads();

#pragma unroll
    for (int kk = 0; kk < 4; ++kk) {
        bfrag A[4], B[4];
#pragma unroll
        for (int mb = 0; mb < 4; ++mb) {
            int pos_l = wp * 64 + mb * 16 + lr;
            A[mb] = *(const bfrag*)&BT[pos_l * 128 + (((kk * 4 + lg) ^ sw(pos_l)) << 3)];
        }
#pragma unroll
        for (int nb = 0; nb < 4; ++nb)
            B[nb] = *(const bfrag*)(WB + (size_t)(WBrow + wo * 64 + nb * 16 + lr) * 128 + kk * 32 + lg * 8);
#pragma unroll
        for (int mb = 0; mb < 4; ++mb)
#pragma unroll
            for (int nb = 0; nb < 4; ++nb)
                acc[mb][nb] = MFMA16(A[mb], B[nb], acc[mb][nb]);
    }

    __syncthreads();  // BT reuse as repack tile

    // epilogue: lane holds 4 consecutive pos (register r) at one o (lane).
    // RoPE active iff s = pos_l&63 < 32  <=>  mb < 2 (uniform).
    const int hh = blockIdx.x;          // posb>>7, block-uniform
#pragma unroll
    for (int mb = 0; mb < 4; ++mb) {
        const bool roped = (mode != 0) && (mb < 2);
#pragma unroll
        for (int nb = 0; nb < 4; ++nb) {
            int o_l = wo * 64 + nb * 16 + lr;
            int pos_l = wp * 64 + mb * 16 + lg * 4;
            ffrag v4 = acc[mb][nb];
            if (roped) {
                int pidx = (o_l & 63) * 2 + (hh >> 6);
                int ridx = (hh & 63) * 2 + wp;          // ww>>6 == wp
                int s0 = mb * 16 + lg * 4;              // quad-aligned, no 64-cross
                int sidx = (pidx * 128 + ridx) * 32 + s0;
                float4 sv4 = *(const float4*)(sinp + sidx);
                float4 cv4 = *(const float4*)(cosp + sidx);
                float sv[4] = {sv4.x, sv4.y, sv4.z, sv4.w};
                float cv[4] = {cv4.x, cv4.y, cv4.z, cv4.w};
#pragma unroll
                for (int r = 0; r < 4; ++r) {
                    float sg = (r & 1) ? sv[r] : -sv[r];    // rotate_half: -even, +odd
                    v4[r] = (mode == 1) ? v4[r] * (cv[r] + sg)        // q
                                        : v4[r] * (1.f + sg) + cv[r]; // k (ref's "+cos")
                }
            }
            s4v pk;
            pk[0] = (short)f2bf(v4[0]); pk[1] = (short)f2bf(v4[1]);
            pk[2] = (short)f2bf(v4[2]); pk[3] = (short)f2bf(v4[3]);
            int slot = pos_l >> 3;
            *(s4v*)&BT[o_l * 128 + ((slot ^ (o_l & 15)) << 3) + (pos_l & 4)] = pk;
        }
    }

    __syncthreads();

    // coalesced store: 8 x dwordx4 per thread (each 16-lane group = 256B row)
#pragma unroll
    for (int it = 0; it < 8; ++it) {
        int g = it * 256 + t;
        int row = g >> 4, slot = g & 15;
        uint4 v = *(const uint4*)&BT[row * 128 + ((slot ^ (row & 15)) << 3)];
        *(uint4*)(dst + (size_t)row * 16384 + pos0 + slot * 8) = v;
    }
}

// ---------------------------------------------------------------------------
// Kernel 3: windowed attention (UNCHANGED from passing round-4 kernel).
// ---------------------------------------------------------------------------
__global__ __launch_bounds__(512, 4) void k_attn(
    const u16* __restrict__ qb, const u16* __restrict__ kbuf,
    const u16* __restrict__ vbuf, u16* __restrict__ ob)
{
    __shared__ u16 Ks[64 * 64];      // [j][d-chunk ^ (j&7)]
    __shared__ u16 Vt[64 * 64];      // [d][j-chunk ^ s(d)], s(d)=(d&7)^((d>>3)&7)
    __shared__ u16 Ps[8][32 * 40];   // per wave: [i_local][j-half 32, pitch 40]
    __shared__ float Lbuf[256];

    const int bp = blockIdx.x;
    const int t = threadIdx.x, w = t >> 6, l = t & 63, lr = l & 15, lg = l >> 4;

    const u16* Qg = qb + (size_t)bp * 16384 + w * 2048;   // wave's 32 q-rows
    const u16* Kg = kbuf + (size_t)bp * 32768;
    const u16* Vg = vbuf + (size_t)bp * 32768;

    bfrag Qf[2][2];
#pragma unroll
    for (int rb = 0; rb < 2; ++rb)
#pragma unroll
        for (int dk = 0; dk < 2; ++dk)
            Qf[rb][dk] = *(const bfrag*)(Qg + (rb * 16 + lr) * 64 + dk * 32 + lg * 8);

    ffrag zf = {0.f, 0.f, 0.f, 0.f};
    ffrag Oacc[2][4];
#pragma unroll
    for (int rb = 0; rb < 2; ++rb)
#pragma unroll
        for (int sb = 0; sb < 4; ++sb) Oacc[rb][sb] = zf;
    float Lp[2] = {0.f, 0.f};

    const int t2 = t & 255, sj = t2 >> 2, sq = t2 & 3;
    const bool isK = (t < 256);
    const u16* gs = (isK ? Kg : Vg) + sj * 64 + sq * 16;

    uint4 r0 = *(const uint4*)gs;              // prefetch chunk 0
    uint4 r1 = *(const uint4*)(gs + 8);

    for (int c = 0; c < 8; ++c) {
        __syncthreads();
        if (isK) {
            *(uint4*)&Ks[sj * 64 + (((sq * 2) ^ (sj & 7)) << 3)] = r0;
            *(uint4*)&Ks[sj * 64 + (((sq * 2 + 1) ^ (sj & 7)) << 3)] = r1;
        } else {
            u16 tmp[16];
            *(uint4*)&tmp[0] = r0;
            *(uint4*)&tmp[8] = r1;
            const int chunk = sj >> 3, jl = sj & 7;
#pragma unroll
            for (int e = 0; e < 16; ++e) {
                int d = sq * 16 + e;
                int s = (d & 7) ^ ((d >> 3) & 7);
                Vt[d * 64 + ((chunk ^ s) << 3) + jl] = tmp[e];   // V^T[d][j]
            }
        }
        __syncthreads();
        if (c < 7) {
            r0 = *(const uint4*)(gs + (c + 1) * 4096);
            r1 = *(const uint4*)(gs + (c + 1) * 4096 + 8);
        }

#pragma unroll
        for (int jh = 0; jh < 2; ++jh) {
#pragma unroll
            for (int jtl = 0; jtl < 2; ++jtl) {
                const int jt = jh * 2 + jtl;
                bfrag Kf[2];
#pragma unroll
                for (int dk = 0; dk < 2; ++dk)
                    Kf[dk] = *(const bfrag*)&Ks[(jt * 16 + lr) * 64 + (((dk * 4 + lg) ^ (lr & 7)) << 3)];
#pragma unroll
                for (int rb = 0; rb < 2; ++rb) {
                    ffrag sf = zf;
                    sf = MFMA16(Kf[0], Qf[rb][0], sf);   // D[j_loc=lg*4+r][i_loc=lr]
                    sf = MFMA16(Kf[1], Qf[rb][1], sf);
                    float e0 = __expf(sf[0] * 0.125f);   // SCALE = 1/sqrt(64)
                    float e1 = __expf(sf[1] * 0.125f);
                    float e2 = __expf(sf[2] * 0.125f);
                    float e3 = __expf(sf[3] * 0.125f);
                    Lp[rb] += (e0 + e1) + (e2 + e3);
                    s4v pk;
                    pk[0] = (short)f2bf(e0); pk[1] = (short)f2bf(e1);
                    pk[2] = (short)f2bf(e2); pk[3] = (short)f2bf(e3);
                    *(s4v*)&Ps[w][(rb * 16 + lr) * 40 + jtl * 16 + lg * 4] = pk;
                }
            }

            bfrag Vf[4];
#pragma unroll
            for (int sb = 0; sb < 4; ++sb) {
                int d = sb * 16 + lr;
                int s = (d & 7) ^ ((d >> 3) & 7);
                Vf[sb] = *(const bfrag*)&Vt[d * 64 + (((jh * 4 + lg) ^ s) << 3)];
            }
#pragma unroll
            for (int rb = 0; rb < 2; ++rb) {
                bfrag Pf = *(const bfrag*)&Ps[w][(rb * 16 + lr) * 40 + lg * 8];
#pragma unroll
                for (int sb = 0; sb < 4; ++sb)
                    Oacc[rb][sb] = MFMA16(Pf, Vf[sb], Oacc[rb][sb]);  // D[i=lg*4+r][d=lr]
            }
        }
    }

#pragma unroll
    for (int rb = 0; rb < 2; ++rb) {
        float v = Lp[rb];
        v += __shfl_xor(v, 16);
        v += __shfl_xor(v, 32);
        if (lg == 0) Lbuf[w * 32 + rb * 16 + lr] = v;
    }
    u16* og = ob + (size_t)bp * 16384 + w * 2048;
#pragma unroll
    for (int rb = 0; rb < 2; ++rb)
#pragma unroll
        for (int r = 0; r < 4; ++r) {
            float inv = 1.f / Lbuf[w * 32 + rb * 16 + lg * 4 + r];
#pragma unroll
            for (int sb = 0; sb < 4; ++sb)
                og[(rb * 16 + lg * 4 + r) * 64 + sb * 16 + lr] = f2bf(Oacc[rb][sb][r] * inv);
        }
}

// ---------------------------------------------------------------------------
// Kernel 4: out projection out[b][o2][pos] = sum_c2 WoutB[o2][c2]*ob[b][c2][pos].
// ---------------------------------------------------------------------------
__global__ __launch_bounds__(256) void k_out(
    const u16* __restrict__ ob, const u16* __restrict__ WoutB,
    float* __restrict__ out)
{
    __shared__ u16 OT[64 * 128];
    const int t = threadIdx.x, w = t >> 6, l = t & 63, lr = l & 15, lg = l >> 4;
    const int pos0 = blockIdx.x * 64;
    const int b = blockIdx.y;
    const u16* obp = ob + (size_t)b * 8388608;
    float* op = out + (size_t)b * 2097152;

    ffrag zf = {0.f, 0.f, 0.f, 0.f};
    ffrag acc[2][4];
#pragma unroll
    for (int rb = 0; rb < 2; ++rb)
#pragma unroll
        for (int nb = 0; nb < 4; ++nb) acc[rb][nb] = zf;

    for (int kc = 0; kc < 4; ++kc) {
        __syncthreads();
#pragma unroll
        for (int it = 0; it < 4; ++it) {
            int g = it * 256 + t;
            int cl = g >> 3, pk = g & 7;
            uint4 v = *(const uint4*)(obp + (size_t)(kc * 128 + cl) * 16384 + pos0 + pk * 8);
            u16 tmp[8];
            *(uint4*)tmp = v;
#pragma unroll
            for (int e = 0; e < 8; ++e) {
                int pos_l = pk * 8 + e;
                OT[pos_l * 128 + (((cl >> 3) ^ sw(pos_l)) << 3) + (cl & 7)] = tmp[e];
            }
        }
        __syncthreads();

#pragma unroll
        for (int kk = 0; kk < 4; ++kk) {
            bfrag Af[2];
#pragma unroll
            for (int rb = 0; rb < 2; ++rb)
                Af[rb] = *(const bfrag*)(WoutB + (size_t)(w * 32 + rb * 16 + lr) * 512 + kc * 128 + kk * 32 + lg * 8);
#pragma unroll
            for (int nb = 0; nb < 4; ++nb) {
                int pos_l = nb * 16 + lr;
                bfrag B = *(const bfrag*)&OT[pos_l * 128 + (((kk * 4 + lg) ^ sw(pos_l)) << 3)];
#pragma unroll
                for (int rb = 0; rb < 2; ++rb)
                    acc[rb][nb] = MFMA16(Af[rb], B, acc[rb][nb]);
            }
        }
    }

#pragma unroll
    for (int rb = 0; rb < 2; ++rb)
#pragma unroll
        for (int nb = 0; nb < 4; ++nb)
#pragma unroll
            for (int r = 0; r < 4; ++r)
                op[(size_t)(w * 32 + rb * 16 + lg * 4 + r) * 16384 + pos0 + nb * 16 + lr] =
                    acc[rb][nb][r];
}

// ---------------------------------------------------------------------------
extern "C" void kernel_launch(void* const* d_in, const int* in_sizes, int n_in,
                              void* d_out, int out_size, void* d_ws, size_t ws_size,
                              hipStream_t stream) {
    const float* x    = (const float*)d_in[0];
    const float* skip = (const float*)d_in[1];
    const float* sinp = (const float*)d_in[2];
    const float* cosp = (const float*)d_in[3];
    const float* Wq   = (const float*)d_in[4];
    const float* Wkv  = (const float*)d_in[5];
    const float* Wout = (const float*)d_in[6];
    float* out = (float*)d_out;

    // workspace (u16 units): qb 16.7M | kbuf 33.5M | vbuf 33.5M | xb 8.4M | WB | WoutB
    u16* qb    = (u16*)d_ws;
    u16* kbp   = qb + (size_t)16777216;
    u16* vbp   = kbp + (size_t)33554432;
    u16* xbp   = vbp + (size_t)33554432;
    u16* WBp   = xbp + (size_t)8388608;
    u16* WoutB = WBp + (size_t)196608;

    hipLaunchKernelGGL(k_prep, dim3(128), dim3(256), 0, stream,
                       Wq, Wkv, Wout, WBp, WoutB);
    hipLaunchKernelGGL(k_cast, dim3(256, 4), dim3(256), 0, stream,
                       x, skip, xbp);
    hipLaunchKernelGGL(k_proj, dim3(128, 40), dim3(256), 0, stream,
                       xbp, sinp, cosp, WBp, qb, kbp, vbp);
    hipLaunchKernelGGL(k_attn, dim3(1024), dim3(512), 0, stream,
                       qb, kbp, vbp, qb /* in-place output over q */);
    hipLaunchKernelGGL(k_out, dim3(256, 2), dim3(256), 0, stream,
                       qb, WoutB, out);
}